// Round 8
// baseline (244.532 us; speedup 1.0000x reference)
//
#include <hip/hip_runtime.h>
#include <math.h>

// B,N,T,F = 32,512,12,64
#define NN 512
#define TT 12
#define FF 64

typedef float  f32x4   __attribute__((ext_vector_type(4)));
typedef float  f32x16  __attribute__((ext_vector_type(16)));
typedef short  short2v __attribute__((ext_vector_type(2)));
typedef short  short4v __attribute__((ext_vector_type(4)));
typedef short  short8v __attribute__((ext_vector_type(8)));
typedef unsigned int u32;
typedef u32    u32x2   __attribute__((ext_vector_type(2)));
typedef u32    u32x4   __attribute__((ext_vector_type(4)));

static __device__ __forceinline__ u32 cvtpk(float a, float b) {
    u32 p;
    asm("v_cvt_pk_bf16_f32 %0, %1, %2" : "=v"(p) : "v"(a), "v"(b));
    return p;   // low16 = bf16(a), high16 = bf16(b)
}
static __device__ __forceinline__ short f2bf(float f) {
    u32 u = __builtin_bit_cast(u32, f);
    u32 r = u + 0x7FFFu + ((u >> 16) & 1u);   // RNE
    return (short)(r >> 16);
}
static __device__ __forceinline__ float bf2f(short h) {
    u32 u = ((u32)(unsigned short)h) << 16;
    return __builtin_bit_cast(float, u);
}
static __device__ __forceinline__ void cvt4(f32x4 v, short4v& h, short4v& lo) {
    u32 p01 = cvtpk(v[0], v[1]);
    u32 p23 = cvtpk(v[2], v[3]);
    float r0 = v[0] - __builtin_bit_cast(float, p01 << 16);
    float r1 = v[1] - __builtin_bit_cast(float, p01 & 0xffff0000u);
    float r2 = v[2] - __builtin_bit_cast(float, p23 << 16);
    float r3 = v[3] - __builtin_bit_cast(float, p23 & 0xffff0000u);
    u32 q01 = cvtpk(r0, r1);
    u32 q23 = cvtpk(r2, r3);
    u32x2 hh; hh[0] = p01; hh[1] = p23;
    u32x2 qq; qq[0] = q01; qq[1] = q23;
    h  = __builtin_bit_cast(short4v, hh);
    lo = __builtin_bit_cast(short4v, qq);
}
static __device__ __forceinline__ short8v cat44(short4v a, short4v b) {
    return __builtin_shufflevector(a, b, 0, 1, 2, 3, 4, 5, 6, 7);
}

// LDS (bytes), total 35840:
//  main loop : sKH [64][72] @0      sKL @9216      (row-major K tile)
//              sKTH[64][68] @18432  sKTL @27136    (f-major V tile)
//  epilogue  : sAH [128][68] @0     sAL @17408     (normalized agg hi/lo, time-shared)
//              linv f32[256] @34816
#define SMEM_BYTES 35840

__global__ __launch_bounds__(512, 6)
void sgcn8(const float* __restrict__ x, const float* __restrict__ adj,
           const float* __restrict__ W, float* __restrict__ out)
{
    __shared__ __align__(16) char smem[SMEM_BYTES];
    char* sKH  = smem;
    char* sKL  = smem + 9216;
    char* sKTH = smem + 18432;
    char* sKTL = smem + 27136;
    char* sAH  = smem;
    char* sAL  = smem + 17408;
    float* linvLDS = (float*)(smem + 34816);

    // XCD-grouped swizzle: 2 WGs per (b,t) adjacent on one XCD; nwg=768 = 8*96
    const int d   = blockIdx.x;
    const int xcd = d & 7;
    const int s   = d >> 3;               // 0..95
    const int G   = xcd + 8 * (s >> 1);   // 0..383 = b*12 + t
    const int mem = s & 1;
    const int t = G % TT, b = G / TT;
    const int n0 = mem * 256;

    const int tid = threadIdx.x;
    const int w   = tid >> 6;             // wave 0..7 -> n-rows 32w..32w+31
    const int l31 = tid & 63 & 31;
    const int hi2 = (tid >> 5) & 1;
    const int fq  = tid & 15;             // staging: f-quad (floats 4fq..4fq+3)
    const int mq  = tid >> 4;             // staging: row pair (rows 2mq, 2mq+1)
    const int myn = n0 + 32 * w + l31;    // this lane's n (S^T col / PV A row)

    const float K2 = 0.18033688011112042f;   // 0.125 * log2(e)

#define STAGE_WRITE(L0, L1)                                                    \
  {                                                                            \
    short4v h0,q0,h1,q1;                                                       \
    cvt4(L0,h0,q0); cvt4(L1,h1,q1);                                            \
    *(short4v*)(sKH + ((2*mq+0)*72 + 4*fq) * 2) = h0;                          \
    *(short4v*)(sKH + ((2*mq+1)*72 + 4*fq) * 2) = h1;                          \
    *(short4v*)(sKL + ((2*mq+0)*72 + 4*fq) * 2) = q0;                          \
    *(short4v*)(sKL + ((2*mq+1)*72 + 4*fq) * 2) = q1;                          \
    _Pragma("unroll")                                                          \
    for (int j = 0; j < 4; ++j) {                                              \
        short2v th; th[0]=h0[j]; th[1]=h1[j];                                  \
        short2v tl; tl[0]=q0[j]; tl[1]=q1[j];                                  \
        *(short2v*)(sKTH + ((4*fq+j)*68 + 2*mq) * 2) = th;                     \
        *(short2v*)(sKTL + ((4*fq+j)*68 + 2*mq) * 2) = tl;                     \
    }                                                                          \
  }

    // ---- prologue: xn fragments (B-operand of S^T) + tile-0 staging ----
    const float* xnrow = x + ((size_t)(b * NN + myn) * TT + t) * FF;
    f32x4 xa[8];
    #pragma unroll
    for (int ks = 0; ks < 4; ++ks) {
        xa[2*ks]   = *(const f32x4*)(xnrow + ks * 16 + hi2 * 8);
        xa[2*ks+1] = *(const f32x4*)(xnrow + ks * 16 + hi2 * 8 + 4);
    }
    const float* xst = x + ((size_t)(b * NN + 2 * mq) * TT + t) * FF + 4 * fq;
    f32x4 ld0 = *(const f32x4*)(xst);
    f32x4 ld1 = *(const f32x4*)(xst + TT * FF);

    short8v xnH[4], xnL[4];
    #pragma unroll
    for (int ks = 0; ks < 4; ++ks) {
        short4v h0, l0, h1, l1;
        cvt4(xa[2*ks],   h0, l0);
        cvt4(xa[2*ks+1], h1, l1);
        xnH[ks] = cat44(h0, h1);
        xnL[ks] = cat44(l0, l1);
    }
    STAGE_WRITE(ld0, ld1)
    __syncthreads();

    float lpart = 0.f;
    f32x16 agg0, agg1;
    #pragma unroll
    for (int i = 0; i < 16; ++i) { agg0[i] = 0.f; agg1[i] = 0.f; }

    for (int mt = 0; mt < 8; ++mt) {
        const int m0 = mt * 64;

        // T14: issue next-tile loads now; convert+write after the barrier
        f32x4 p0, p1;
        if (mt < 7) {
            const float* xs = x + ((size_t)(b * NN + m0 + 64 + 2 * mq) * TT + t) * FF + 4 * fq;
            p0 = *(const f32x4*)(xs);
            p1 = *(const f32x4*)(xs + TT * FF);
        }

        // ---- S^T = Xm*Xn^T (A = K rows from LDS, B = xn regs) ----
        // D: col = n = l31 (lane), row = m = mb*32 + (r&3)+8*(r>>2)+4*hi2 (regs)
        short8v pa[4];
        #pragma unroll
        for (int mb = 0; mb < 2; ++mb) {
            const float* arow = adj + (size_t)myn * NN + m0 + mb * 32 + 4 * hi2;
            f32x4 av0 = *(const f32x4*)(arow);
            f32x4 av1 = *(const f32x4*)(arow + 8);
            f32x4 av2 = *(const f32x4*)(arow + 16);
            f32x4 av3 = *(const f32x4*)(arow + 24);

            f32x16 sc;
            #pragma unroll
            for (int i = 0; i < 16; ++i) sc[i] = 0.f;
            #pragma unroll
            for (int ks = 0; ks < 4; ++ks) {
                short8v kH = *(const short8v*)(sKH + ((mb*32 + l31) * 72 + ks*16 + hi2*8) * 2);
                short8v kL = *(const short8v*)(sKL + ((mb*32 + l31) * 72 + ks*16 + hi2*8) * 2);
                sc = __builtin_amdgcn_mfma_f32_32x32x16_bf16(kH, xnH[ks], sc, 0, 0, 0);
                sc = __builtin_amdgcn_mfma_f32_32x32x16_bf16(kH, xnL[ks], sc, 0, 0, 0);
                sc = __builtin_amdgcn_mfma_f32_32x32x16_bf16(kL, xnH[ks], sc, 0, 0, 0);
            }

            // maxless softmax, fully lane-local (denominator WITHOUT adj)
            float p[16];
            #pragma unroll
            for (int r = 0; r < 16; ++r) {
                p[r] = __builtin_amdgcn_exp2f(sc[r] * K2);
                lpart += p[r];
            }
            p[0]  *= av0[0]; p[1]  *= av0[1]; p[2]  *= av0[2]; p[3]  *= av0[3];
            p[4]  *= av1[0]; p[5]  *= av1[1]; p[6]  *= av1[2]; p[7]  *= av1[3];
            p[8]  *= av2[0]; p[9]  *= av2[1]; p[10] *= av2[2]; p[11] *= av2[3];
            p[12] *= av3[0]; p[13] *= av3[1]; p[14] *= av3[2]; p[15] *= av3[3];

            // P (n=lane, m=regs) -> PV A-frag (row=n=lane, k=m) via half-exchange
            u32 A0 = cvtpk(p[0],  p[1]),  A1 = cvtpk(p[2],  p[3]);
            u32 B0 = cvtpk(p[4],  p[5]),  B1 = cvtpk(p[6],  p[7]);
            u32 A2 = cvtpk(p[8],  p[9]),  A3 = cvtpk(p[10], p[11]);
            u32 B2 = cvtpk(p[12], p[13]), B3 = cvtpk(p[14], p[15]);
            u32 sA0 = (u32)__shfl_xor((int)A0, 32), sA1 = (u32)__shfl_xor((int)A1, 32);
            u32 sB0 = (u32)__shfl_xor((int)B0, 32), sB1 = (u32)__shfl_xor((int)B1, 32);
            u32 sA2 = (u32)__shfl_xor((int)A2, 32), sA3 = (u32)__shfl_xor((int)A3, 32);
            u32 sB2 = (u32)__shfl_xor((int)B2, 32), sB3 = (u32)__shfl_xor((int)B3, 32);
            u32x4 e, o;
            e[0] = hi2 ? sB0 : A0;  e[1] = hi2 ? sB1 : A1;
            e[2] = hi2 ? B0 : sA0;  e[3] = hi2 ? B1 : sA1;
            o[0] = hi2 ? sB2 : A2;  o[1] = hi2 ? sB3 : A3;
            o[2] = hi2 ? B2 : sA2;  o[3] = hi2 ? B3 : sA3;
            pa[2*mb]     = __builtin_bit_cast(short8v, e);
            pa[2*mb + 1] = __builtin_bit_cast(short8v, o);
        }

        // ---- PV: agg[n][f] += P * V (B-frags = rows of f-major tile) ----
        #pragma unroll
        for (int ks = 0; ks < 4; ++ks) {
            {   // f-block 0 -> agg0
                short4v v0 = *(const short4v*)(sKTH + (l31 * 68 + ks*16 + hi2*8) * 2);
                short4v v1 = *(const short4v*)(sKTH + (l31 * 68 + ks*16 + hi2*8 + 4) * 2);
                short4v u0 = *(const short4v*)(sKTL + (l31 * 68 + ks*16 + hi2*8) * 2);
                short4v u1 = *(const short4v*)(sKTL + (l31 * 68 + ks*16 + hi2*8 + 4) * 2);
                agg0 = __builtin_amdgcn_mfma_f32_32x32x16_bf16(pa[ks], cat44(v0, v1), agg0, 0, 0, 0);
                agg0 = __builtin_amdgcn_mfma_f32_32x32x16_bf16(pa[ks], cat44(u0, u1), agg0, 0, 0, 0);
            }
            {   // f-block 1 -> agg1
                short4v v0 = *(const short4v*)(sKTH + ((32 + l31) * 68 + ks*16 + hi2*8) * 2);
                short4v v1 = *(const short4v*)(sKTH + ((32 + l31) * 68 + ks*16 + hi2*8 + 4) * 2);
                short4v u0 = *(const short4v*)(sKTL + ((32 + l31) * 68 + ks*16 + hi2*8) * 2);
                short4v u1 = *(const short4v*)(sKTL + ((32 + l31) * 68 + ks*16 + hi2*8 + 4) * 2);
                agg1 = __builtin_amdgcn_mfma_f32_32x32x16_bf16(pa[ks], cat44(v0, v1), agg1, 0, 0, 0);
                agg1 = __builtin_amdgcn_mfma_f32_32x32x16_bf16(pa[ks], cat44(u0, u1), agg1, 0, 0, 0);
            }
        }

        __syncthreads();                       // all waves done reading tile mt
        if (mt < 7) STAGE_WRITE(p0, p1)
        __syncthreads();                       // tile mt+1 visible
    }

    // ---- epilogue: normalize, transpose via time-shared 128-row LDS, GEMM ----
    float lf = lpart + __shfl_xor(lpart, 32);
    if (hi2 == 0) linvLDS[32 * w + l31] = 0.125f / lf;   // fold post-softmax 1/8
    __syncthreads();                                      // linv visible

    short8v gH[4], gL[4];

#define AGG_STORE(ROFF)                                                        \
    _Pragma("unroll")                                                          \
    for (int r = 0; r < 16; ++r) {                                             \
        int row = 32 * w + (r & 3) + 8 * (r >> 2) + 4 * hi2;                   \
        float nv = linvLDS[row];                                               \
        float v0 = agg0[r] * nv;                                               \
        float v1 = agg1[r] * nv;                                               \
        short h0 = f2bf(v0); short g0 = f2bf(v0 - bf2f(h0));                   \
        short h1 = f2bf(v1); short g1 = f2bf(v1 - bf2f(h1));                   \
        *(short*)(sAH + ((row - (ROFF)) * 68 + l31) * 2)      = h0;            \
        *(short*)(sAL + ((row - (ROFF)) * 68 + l31) * 2)      = g0;            \
        *(short*)(sAH + ((row - (ROFF)) * 68 + 32 + l31) * 2) = h1;            \
        *(short*)(sAL + ((row - (ROFF)) * 68 + 32 + l31) * 2) = g1;            \
    }

#define AGG_LOAD(ROFF)                                                         \
    _Pragma("unroll")                                                          \
    for (int ks = 0; ks < 4; ++ks) {                                           \
        int rr = 32 * w - (ROFF) + l31;                                        \
        short4v a0 = *(const short4v*)(sAH + (rr * 68 + ks*16 + hi2*8) * 2);   \
        short4v a1 = *(const short4v*)(sAH + (rr * 68 + ks*16 + hi2*8 + 4) * 2);\
        short4v c0 = *(const short4v*)(sAL + (rr * 68 + ks*16 + hi2*8) * 2);   \
        short4v c1 = *(const short4v*)(sAL + (rr * 68 + ks*16 + hi2*8 + 4) * 2);\
        gH[ks] = cat44(a0, a1);                                                \
        gL[ks] = cat44(c0, c1);                                                \
    }

    if (w < 4) AGG_STORE(0)
    __syncthreads();
    if (w < 4) AGG_LOAD(0)
    __syncthreads();
    if (w >= 4) AGG_STORE(128)
    __syncthreads();
    if (w >= 4) AGG_LOAD(128)

    // out = relu(aggN * W^T): B = W[k=f][col=o=lane] -> each lane holds its W row
    #pragma unroll
    for (int ob = 0; ob < 2; ++ob) {
        short8v wHreg[4], wLreg[4];
        #pragma unroll
        for (int ks = 0; ks < 4; ++ks) {
            const float* wp = W + (size_t)(ob * 32 + l31) * FF + ks * 16 + hi2 * 8;
            f32x4 wa = *(const f32x4*)(wp);
            f32x4 wb = *(const f32x4*)(wp + 4);
            short4v h0, l0, h1, l1;
            cvt4(wa, h0, l0);
            cvt4(wb, h1, l1);
            wHreg[ks] = cat44(h0, h1);
            wLreg[ks] = cat44(l0, l1);
        }
        f32x16 oc;
        #pragma unroll
        for (int i = 0; i < 16; ++i) oc[i] = 0.f;
        #pragma unroll
        for (int ks = 0; ks < 4; ++ks) {
            oc = __builtin_amdgcn_mfma_f32_32x32x16_bf16(gH[ks], wHreg[ks], oc, 0, 0, 0);
            oc = __builtin_amdgcn_mfma_f32_32x32x16_bf16(gH[ks], wLreg[ks], oc, 0, 0, 0);
            oc = __builtin_amdgcn_mfma_f32_32x32x16_bf16(gL[ks], wHreg[ks], oc, 0, 0, 0);
        }
        #pragma unroll
        for (int r = 0; r < 16; ++r) {
            int row = 32 * w + (r & 3) + 8 * (r >> 2) + 4 * hi2;
            out[((size_t)(b * NN + n0 + row) * TT + t) * FF + 32 * ob + l31] = fmaxf(oc[r], 0.f);
        }
    }
#undef STAGE_WRITE
#undef AGG_STORE
#undef AGG_LOAD
}

extern "C" void kernel_launch(void* const* d_in, const int* in_sizes, int n_in,
                              void* d_out, int out_size, void* d_ws, size_t ws_size,
                              hipStream_t stream) {
    const float* x   = (const float*)d_in[0];
    const float* adj = (const float*)d_in[1];
    const float* W   = (const float*)d_in[2];
    float* outp = (float*)d_out;

    sgcn8<<<dim3(768), dim3(512), 0, stream>>>(x, adj, W, outp);
}

// Round 10
// 129.498 us; speedup vs baseline: 1.8883x; 1.8883x over previous
//
#include <hip/hip_runtime.h>
#include <math.h>

// B,N,T,F = 32,512,12,64
#define NN 512
#define TT 12
#define FF 64

typedef float  f32x4   __attribute__((ext_vector_type(4)));
typedef float  f32x16  __attribute__((ext_vector_type(16)));
typedef short  short4v __attribute__((ext_vector_type(4)));
typedef short  short8v __attribute__((ext_vector_type(8)));
typedef _Float16 h16x4 __attribute__((ext_vector_type(4)));
typedef _Float16 h16x8 __attribute__((ext_vector_type(8)));
typedef unsigned int u32;
typedef u32    u32x4   __attribute__((ext_vector_type(4)));

static __device__ __forceinline__ u32 pkrtz(float a, float b) {
    u32 p;
    asm("v_cvt_pkrtz_f16_f32 %0, %1, %2" : "=v"(p) : "v"(a), "v"(b));
    return p;   // low16 = fp16(a), high16 = fp16(b)
}
// f32x4 -> fp16 hi (RNE) + fp16 residual (exact subtract, then RNE)
static __device__ __forceinline__ void cvt4h(f32x4 v, short4v& h, short4v& lo) {
    h16x4 hh, ll;
    #pragma unroll
    for (int j = 0; j < 4; ++j) {
        _Float16 a = (_Float16)v[j];
        hh[j] = a;
        ll[j] = (_Float16)(v[j] - (float)a);
    }
    h  = __builtin_bit_cast(short4v, hh);
    lo = __builtin_bit_cast(short4v, ll);
}
static __device__ __forceinline__ short8v cat44(short4v a, short4v b) {
    return __builtin_shufflevector(a, b, 0, 1, 2, 3, 4, 5, 6, 7);
}
static __device__ __forceinline__ f32x16 mfmah(short8v a, short8v b, f32x16 c) {
    return __builtin_amdgcn_mfma_f32_32x32x16_f16(
        __builtin_bit_cast(h16x8, a), __builtin_bit_cast(h16x8, b), c, 0, 0, 0);
}

// LDS (bytes), total 26624:
//  main loop : sKH [64][68] @0      (K tile hi, row-major)
//              sKL [64][68] @8704   (K tile lo, row-major)
//              sKTH[64][68] @17408  (V tile hi, f-major)
//              linv f32[128] @26112
//  epilogue  : sA  [128][68] fp16 @0 (normalized agg hi; fits in sKH+sKL region)
#define SMEM_BYTES 26624

__global__ __launch_bounds__(256, 4)
void sgcn10(const float* __restrict__ x, const float* __restrict__ adj,
            const float* __restrict__ W, float* __restrict__ out)
{
    __shared__ __align__(16) char smem[SMEM_BYTES];
    char* sKH  = smem;
    char* sKL  = smem + 8704;
    char* sKTH = smem + 17408;
    char* sA   = smem;
    float* linvLDS = (float*)(smem + 26112);

    // XCD-grouped swizzle: 4 WGs per (b,t) adjacent on one XCD (round-7 mapping)
    const int d   = blockIdx.x;
    const int xcd = d & 7;
    const int s   = d >> 3;
    const int G   = xcd + 8 * (s >> 2);   // 0..383 = b*12 + t
    const int mem = s & 3;
    const int t = G % TT, b = G / TT;
    const int n0 = mem * 128;

    const int tid = threadIdx.x;
    const int w   = tid >> 6;             // wave -> n-rows 32w..32w+31
    const int l31 = tid & 31;
    const int hi2 = (tid >> 5) & 1;
    const int fq  = tid & 15;             // staging: f-quad (floats 4fq..4fq+3)
    const int mq  = tid >> 4;             // staging: rows 4mq..4mq+3
    const int myn = n0 + 32 * w + l31;    // this lane's n (S^T col / PV A row)

    const float K2 = 0.18033688011112042f;   // 0.125 * log2(e)
    // uniform logit shift (softmax-invariant): keeps max P ~ e^(16-6)=2.2e4 < fp16 max 65504
    const float SH2 = 8.656170245333781f;    // 6 * log2(e)

#define STAGE_WRITE(L0, L1, L2, L3)                                            \
  {                                                                            \
    short4v h0,q0,h1,q1,h2,q2,h3,q3;                                           \
    cvt4h(L0,h0,q0); cvt4h(L1,h1,q1); cvt4h(L2,h2,q2); cvt4h(L3,h3,q3);        \
    *(short4v*)(sKH + ((4*mq+0)*68 + 4*fq) * 2) = h0;                          \
    *(short4v*)(sKH + ((4*mq+1)*68 + 4*fq) * 2) = h1;                          \
    *(short4v*)(sKH + ((4*mq+2)*68 + 4*fq) * 2) = h2;                          \
    *(short4v*)(sKH + ((4*mq+3)*68 + 4*fq) * 2) = h3;                          \
    *(short4v*)(sKL + ((4*mq+0)*68 + 4*fq) * 2) = q0;                          \
    *(short4v*)(sKL + ((4*mq+1)*68 + 4*fq) * 2) = q1;                          \
    *(short4v*)(sKL + ((4*mq+2)*68 + 4*fq) * 2) = q2;                          \
    *(short4v*)(sKL + ((4*mq+3)*68 + 4*fq) * 2) = q3;                          \
    _Pragma("unroll")                                                          \
    for (int j = 0; j < 4; ++j) {                                              \
        short4v th; th[0]=h0[j]; th[1]=h1[j]; th[2]=h2[j]; th[3]=h3[j];        \
        *(short4v*)(sKTH + ((4*fq+j)*68 + 4*mq) * 2) = th;                     \
    }                                                                          \
  }

    // ---- prologue: xn fragments (B-operand of S^T, fp16 hi) + tile-0 staging ----
    const float* xnrow = x + ((size_t)(b * NN + myn) * TT + t) * FF;
    short8v xnH[4];
    #pragma unroll
    for (int ks = 0; ks < 4; ++ks) {
        f32x4 a0 = *(const f32x4*)(xnrow + ks * 16 + hi2 * 8);
        f32x4 a1 = *(const f32x4*)(xnrow + ks * 16 + hi2 * 8 + 4);
        short4v h0, l0, h1, l1;
        cvt4h(a0, h0, l0);
        cvt4h(a1, h1, l1);
        xnH[ks] = cat44(h0, h1);
    }
    {
        const float* xst = x + ((size_t)(b * NN + 4 * mq) * TT + t) * FF + 4 * fq;
        f32x4 ld0 = *(const f32x4*)(xst);
        f32x4 ld1 = *(const f32x4*)(xst + TT * FF);
        f32x4 ld2 = *(const f32x4*)(xst + 2 * TT * FF);
        f32x4 ld3 = *(const f32x4*)(xst + 3 * TT * FF);
        STAGE_WRITE(ld0, ld1, ld2, ld3)
    }
    __syncthreads();

    float lpart = 0.f;
    f32x16 agg0, agg1;
    #pragma unroll
    for (int i = 0; i < 16; ++i) { agg0[i] = 0.f; agg1[i] = 0.f; }

    for (int mt = 0; mt < 8; ++mt) {
        const int m0 = mt * 64;

        // T14: issue next-tile loads now; convert+write after the barrier
        f32x4 p0, p1, p2, p3;
        if (mt < 7) {
            const float* xs = x + ((size_t)(b * NN + m0 + 64 + 4 * mq) * TT + t) * FF + 4 * fq;
            p0 = *(const f32x4*)(xs);
            p1 = *(const f32x4*)(xs + TT * FF);
            p2 = *(const f32x4*)(xs + 2 * TT * FF);
            p3 = *(const f32x4*)(xs + 3 * TT * FF);
        }

        // ---- S^T = Xm*Xn^T, 2-term fp16 (Kh + Kl vs xn-hi) ----
        // D: col = n = l31 (lane), row = m = mb*32 + (r&3)+8*(r>>2)+4*hi2 (regs)
        short8v pa[4];
        #pragma unroll
        for (int mb = 0; mb < 2; ++mb) {
            const float* arow = adj + (size_t)myn * NN + m0 + mb * 32 + 4 * hi2;

            f32x16 sc;
            #pragma unroll
            for (int i = 0; i < 16; ++i) sc[i] = 0.f;
            #pragma unroll
            for (int ks = 0; ks < 4; ++ks) {
                short4v k0 = *(const short4v*)(sKH + ((mb*32 + l31) * 68 + ks*16 + hi2*8) * 2);
                short4v k1 = *(const short4v*)(sKH + ((mb*32 + l31) * 68 + ks*16 + hi2*8 + 4) * 2);
                short4v q0 = *(const short4v*)(sKL + ((mb*32 + l31) * 68 + ks*16 + hi2*8) * 2);
                short4v q1 = *(const short4v*)(sKL + ((mb*32 + l31) * 68 + ks*16 + hi2*8 + 4) * 2);
                sc = mfmah(cat44(k0, k1), xnH[ks], sc);
                sc = mfmah(cat44(q0, q1), xnH[ks], sc);
            }

            // maxless softmax with uniform shift, fully lane-local
            float p[16];
            #pragma unroll
            for (int r = 0; r < 16; ++r) {
                p[r] = __builtin_amdgcn_exp2f(sc[r] * K2 - SH2);
                lpart += p[r];                 // denominator WITHOUT adj (shift cancels)
            }
            {   // post-softmax adj mask
                f32x4 av0 = *(const f32x4*)(arow);
                f32x4 av1 = *(const f32x4*)(arow + 8);
                p[0] *= av0[0]; p[1] *= av0[1]; p[2] *= av0[2]; p[3] *= av0[3];
                p[4] *= av1[0]; p[5] *= av1[1]; p[6] *= av1[2]; p[7] *= av1[3];
                f32x4 av2 = *(const f32x4*)(arow + 16);
                f32x4 av3 = *(const f32x4*)(arow + 24);
                p[8]  *= av2[0]; p[9]  *= av2[1]; p[10] *= av2[2]; p[11] *= av2[3];
                p[12] *= av3[0]; p[13] *= av3[1]; p[14] *= av3[2]; p[15] *= av3[3];
            }

            // P (n=lane, m=regs) -> PV A-frag (row=n=lane, k=m) via half-exchange
            u32 A0 = pkrtz(p[0],  p[1]),  A1 = pkrtz(p[2],  p[3]);
            u32 B0 = pkrtz(p[4],  p[5]),  B1 = pkrtz(p[6],  p[7]);
            u32 A2 = pkrtz(p[8],  p[9]),  A3 = pkrtz(p[10], p[11]);
            u32 B2 = pkrtz(p[12], p[13]), B3 = pkrtz(p[14], p[15]);
            u32 sA0 = (u32)__shfl_xor((int)A0, 32), sA1 = (u32)__shfl_xor((int)A1, 32);
            u32 sB0 = (u32)__shfl_xor((int)B0, 32), sB1 = (u32)__shfl_xor((int)B1, 32);
            u32 sA2 = (u32)__shfl_xor((int)A2, 32), sA3 = (u32)__shfl_xor((int)A3, 32);
            u32 sB2 = (u32)__shfl_xor((int)B2, 32), sB3 = (u32)__shfl_xor((int)B3, 32);
            u32x4 e, o;
            e[0] = hi2 ? sB0 : A0;  e[1] = hi2 ? sB1 : A1;
            e[2] = hi2 ? B0 : sA0;  e[3] = hi2 ? B1 : sA1;
            o[0] = hi2 ? sB2 : A2;  o[1] = hi2 ? sB3 : A3;
            o[2] = hi2 ? B2 : sA2;  o[3] = hi2 ? B3 : sA3;
            pa[2*mb]     = __builtin_bit_cast(short8v, e);
            pa[2*mb + 1] = __builtin_bit_cast(short8v, o);
        }

        // ---- PV: agg[n][f] += P * V, 1-term fp16 (V hi only) ----
        #pragma unroll
        for (int ks = 0; ks < 4; ++ks) {
            short4v v0 = *(const short4v*)(sKTH + (l31 * 68 + ks*16 + hi2*8) * 2);
            short4v v1 = *(const short4v*)(sKTH + (l31 * 68 + ks*16 + hi2*8 + 4) * 2);
            agg0 = mfmah(pa[ks], cat44(v0, v1), agg0);
            short4v w0 = *(const short4v*)(sKTH + ((32 + l31) * 68 + ks*16 + hi2*8) * 2);
            short4v w1 = *(const short4v*)(sKTH + ((32 + l31) * 68 + ks*16 + hi2*8 + 4) * 2);
            agg1 = mfmah(pa[ks], cat44(w0, w1), agg1);
        }

        __syncthreads();                       // all waves done reading tile mt
        if (mt < 7) STAGE_WRITE(p0, p1, p2, p3)
        __syncthreads();                       // tile mt+1 visible
    }

    // ---- epilogue ----
    float lf = lpart + __shfl_xor(lpart, 32);
    if (hi2 == 0) linvLDS[32 * w + l31] = 0.125f / lf;   // fold post-softmax 1/8
    __syncthreads();                                      // main-loop LDS free; linv visible

    // normalized agg -> sA (fp16 hi only)
    #pragma unroll
    for (int r = 0; r < 16; ++r) {
        int row = 32 * w + (r & 3) + 8 * (r >> 2) + 4 * hi2;
        float nv = linvLDS[row];
        _Float16 h0 = (_Float16)(agg0[r] * nv);
        _Float16 h1 = (_Float16)(agg1[r] * nv);
        *(short*)(sA + (row * 68 + l31) * 2)      = __builtin_bit_cast(short, h0);
        *(short*)(sA + (row * 68 + 32 + l31) * 2) = __builtin_bit_cast(short, h1);
    }
    __syncthreads();

    // A-frags: lane = n reads its own row's f-slices
    short8v gH[4];
    #pragma unroll
    for (int ks = 0; ks < 4; ++ks) {
        short4v a0 = *(const short4v*)(sA + ((32*w + l31) * 68 + ks*16 + hi2*8) * 2);
        short4v a1 = *(const short4v*)(sA + ((32*w + l31) * 68 + ks*16 + hi2*8 + 4) * 2);
        gH[ks] = cat44(a0, a1);
    }

    // out = relu(aggN * W^T): B = W row per lane, 2-term W-split (Wh + Wl)
    #pragma unroll
    for (int ob = 0; ob < 2; ++ob) {
        short8v wHreg[4], wLreg[4];
        #pragma unroll
        for (int ks = 0; ks < 4; ++ks) {
            const float* wp = W + (size_t)(ob * 32 + l31) * FF + ks * 16 + hi2 * 8;
            f32x4 wa = *(const f32x4*)(wp);
            f32x4 wb = *(const f32x4*)(wp + 4);
            short4v h0, l0, h1, l1;
            cvt4h(wa, h0, l0);
            cvt4h(wb, h1, l1);
            wHreg[ks] = cat44(h0, h1);
            wLreg[ks] = cat44(l0, l1);
        }
        f32x16 oc;
        #pragma unroll
        for (int i = 0; i < 16; ++i) oc[i] = 0.f;
        #pragma unroll
        for (int ks = 0; ks < 4; ++ks) {
            oc = mfmah(gH[ks], wHreg[ks], oc);
            oc = mfmah(gH[ks], wLreg[ks], oc);
        }
        #pragma unroll
        for (int r = 0; r < 16; ++r) {
            int row = 32 * w + (r & 3) + 8 * (r >> 2) + 4 * hi2;
            out[((size_t)(b * NN + n0 + row) * TT + t) * FF + 32 * ob + l31] = fmaxf(oc[r], 0.f);
        }
    }
#undef STAGE_WRITE
}

extern "C" void kernel_launch(void* const* d_in, const int* in_sizes, int n_in,
                              void* d_out, int out_size, void* d_ws, size_t ws_size,
                              hipStream_t stream) {
    const float* x   = (const float*)d_in[0];
    const float* adj = (const float*)d_in[1];
    const float* W   = (const float*)d_in[2];
    float* outp = (float*)d_out;

    sgcn10<<<dim3(1536), dim3(256), 0, stream>>>(x, adj, W, outp);
}

// Round 11
// 98.531 us; speedup vs baseline: 2.4818x; 1.3143x over previous
//
#include <hip/hip_runtime.h>
#include <math.h>

// B,N,T,F = 32,512,12,64
#define NN 512
#define TT 12
#define FF 64

typedef float  f32x4   __attribute__((ext_vector_type(4)));
typedef float  f32x16  __attribute__((ext_vector_type(16)));
typedef short  short4v __attribute__((ext_vector_type(4)));
typedef short  short8v __attribute__((ext_vector_type(8)));
typedef _Float16 h16x4 __attribute__((ext_vector_type(4)));
typedef _Float16 h16x8 __attribute__((ext_vector_type(8)));
typedef unsigned int u32;
typedef u32    u32x4   __attribute__((ext_vector_type(4)));

static __device__ __forceinline__ u32 pkrtz(float a, float b) {
    u32 p;
    asm("v_cvt_pkrtz_f16_f32 %0, %1, %2" : "=v"(p) : "v"(a), "v"(b));
    return p;   // low16 = fp16(a), high16 = fp16(b)
}
// f32x4 -> fp16 hi (RNE) + fp16 residual (exact subtract, then RNE)
static __device__ __forceinline__ void cvt4h(f32x4 v, short4v& h, short4v& lo) {
    h16x4 hh, ll;
    #pragma unroll
    for (int j = 0; j < 4; ++j) {
        _Float16 a = (_Float16)v[j];
        hh[j] = a;
        ll[j] = (_Float16)(v[j] - (float)a);
    }
    h  = __builtin_bit_cast(short4v, hh);
    lo = __builtin_bit_cast(short4v, ll);
}
static __device__ __forceinline__ short8v cat44(short4v a, short4v b) {
    return __builtin_shufflevector(a, b, 0, 1, 2, 3, 4, 5, 6, 7);
}
static __device__ __forceinline__ f32x16 mfmah(short8v a, short8v b, f32x16 c) {
    return __builtin_amdgcn_mfma_f32_32x32x16_f16(
        __builtin_bit_cast(h16x8, a), __builtin_bit_cast(h16x8, b), c, 0, 0, 0);
}

// LDS (bytes), total 26624:
//  main loop : sKH [64][68] @0      (K tile hi, row-major)
//              sKL [64][68] @8704   (K tile lo, row-major)
//              sKTH[64][68] @17408  (V tile hi, f-major)
//              linv f32[128] @26112
//  epilogue  : sA  [128][68] fp16 @0 (normalized agg hi; fits in sKH+sKL region)
#define SMEM_BYTES 26624

__global__ __launch_bounds__(256, 4)
void sgcn11(const float* __restrict__ x, const float* __restrict__ adj,
            const float* __restrict__ W, float* __restrict__ out)
{
    __shared__ __align__(16) char smem[SMEM_BYTES];
    char* sKH  = smem;
    char* sKL  = smem + 8704;
    char* sKTH = smem + 17408;
    char* sA   = smem;
    float* linvLDS = (float*)(smem + 26112);

    // XCD-grouped swizzle: 4 WGs per (b,t) adjacent on one XCD
    const int d   = blockIdx.x;
    const int xcd = d & 7;
    const int s   = d >> 3;
    const int G   = xcd + 8 * (s >> 2);   // 0..383 = b*12 + t
    const int mem = s & 3;
    const int t = G % TT, b = G / TT;
    const int n0 = mem * 128;

    const int tid = threadIdx.x;
    const int w   = tid >> 6;             // wave -> n-rows 32w..32w+31
    const int l31 = tid & 31;
    const int hi2 = (tid >> 5) & 1;
    const int fq  = tid & 15;             // staging: f-quad (floats 4fq..4fq+3)
    const int mq  = tid >> 4;             // staging: rows 4mq..4mq+3
    const int myn = n0 + 32 * w + l31;    // this lane's n (S^T col / PV A row)

    const float K2 = 0.18033688011112042f;   // 0.125 * log2(e)
    // uniform logit shift (softmax-invariant): keeps max P ~ e^(16-6)=2.2e4 < fp16 max 65504
    const float SH2 = 8.656170245333781f;    // 6 * log2(e)

    // ---- prologue: xn fragments (fp16 hi) + tile-0 staging ----
    const float* xnrow = x + ((size_t)(b * NN + myn) * TT + t) * FF;
    short8v xnH[4];
    #pragma unroll
    for (int ks = 0; ks < 4; ++ks) {
        f32x4 a0 = *(const f32x4*)(xnrow + ks * 16 + hi2 * 8);
        f32x4 a1 = *(const f32x4*)(xnrow + ks * 16 + hi2 * 8 + 4);
        short4v h0, l0, h1, l1;
        cvt4h(a0, h0, l0);
        cvt4h(a1, h1, l1);
        xnH[ks] = cat44(h0, h1);
    }

    // staged-tile register state (converted early, written between barriers)
    short4v sh[4], sq[4];   // K hi / K lo rows 4mq..4mq+3

#define STAGE_CONVERT(L0, L1, L2, L3)                                          \
    { cvt4h(L0, sh[0], sq[0]); cvt4h(L1, sh[1], sq[1]);                        \
      cvt4h(L2, sh[2], sq[2]); cvt4h(L3, sh[3], sq[3]); }

#define STAGE_LDS_WRITE                                                        \
  {                                                                            \
    _Pragma("unroll")                                                          \
    for (int j = 0; j < 4; ++j) {                                              \
        *(short4v*)(sKH + ((4*mq+j)*68 + 4*fq) * 2) = sh[j];                   \
        *(short4v*)(sKL + ((4*mq+j)*68 + 4*fq) * 2) = sq[j];                   \
    }                                                                          \
    _Pragma("unroll")                                                          \
    for (int j = 0; j < 4; ++j) {                                              \
        short4v th; th[0]=sh[0][j]; th[1]=sh[1][j]; th[2]=sh[2][j]; th[3]=sh[3][j]; \
        *(short4v*)(sKTH + ((4*fq+j)*68 + 4*mq) * 2) = th;                     \
    }                                                                          \
  }

    {
        const float* xst = x + ((size_t)(b * NN + 4 * mq) * TT + t) * FF + 4 * fq;
        f32x4 ld0 = *(const f32x4*)(xst);
        f32x4 ld1 = *(const f32x4*)(xst + TT * FF);
        f32x4 ld2 = *(const f32x4*)(xst + 2 * TT * FF);
        f32x4 ld3 = *(const f32x4*)(xst + 3 * TT * FF);
        STAGE_CONVERT(ld0, ld1, ld2, ld3)
        STAGE_LDS_WRITE
    }
    __syncthreads();

    float lp4[4] = {0.f, 0.f, 0.f, 0.f};     // 4-way partial denominator (breaks FADD chain)
    f32x16 agg0, agg1;
    #pragma unroll
    for (int i = 0; i < 16; ++i) { agg0[i] = 0.f; agg1[i] = 0.f; }

    for (int mt = 0; mt < 8; ++mt) {
        const int m0 = mt * 64;

        // T14: issue next-tile staging loads first (longest latency)
        f32x4 p0, p1, p2, p3;
        if (mt < 7) {
            const float* xs = x + ((size_t)(b * NN + m0 + 64 + 4 * mq) * TT + t) * FF + 4 * fq;
            p0 = *(const f32x4*)(xs);
            p1 = *(const f32x4*)(xs + TT * FF);
            p2 = *(const f32x4*)(xs + 2 * TT * FF);
            p3 = *(const f32x4*)(xs + 3 * TT * FF);
        }

        // adj prefetch for mb0 BEFORE the MFMAs (hidden under QK0)
        const float* arow0 = adj + (size_t)myn * NN + m0 + 4 * hi2;
        f32x4 a00 = *(const f32x4*)(arow0);
        f32x4 a01 = *(const f32x4*)(arow0 + 8);
        f32x4 a02 = *(const f32x4*)(arow0 + 16);
        f32x4 a03 = *(const f32x4*)(arow0 + 24);

        short8v pa[4];

        // ---- QK0: S^T rows m=0..31 of this tile ----
        f32x16 sc;
        #pragma unroll
        for (int i = 0; i < 16; ++i) sc[i] = 0.f;
        #pragma unroll
        for (int ks = 0; ks < 4; ++ks) {
            short4v k0 = *(const short4v*)(sKH + (l31 * 68 + ks*16 + hi2*8) * 2);
            short4v k1 = *(const short4v*)(sKH + (l31 * 68 + ks*16 + hi2*8 + 4) * 2);
            short4v q0 = *(const short4v*)(sKL + (l31 * 68 + ks*16 + hi2*8) * 2);
            short4v q1 = *(const short4v*)(sKL + (l31 * 68 + ks*16 + hi2*8 + 4) * 2);
            sc = mfmah(cat44(k0, k1), xnH[ks], sc);
            sc = mfmah(cat44(q0, q1), xnH[ks], sc);
        }

        // adj prefetch for mb1 (issued now, consumed after SM0+PV01)
        const float* arow1 = adj + (size_t)myn * NN + m0 + 32 + 4 * hi2;
        f32x4 a10 = *(const f32x4*)(arow1);
        f32x4 a11 = *(const f32x4*)(arow1 + 8);
        f32x4 a12 = *(const f32x4*)(arow1 + 16);
        f32x4 a13 = *(const f32x4*)(arow1 + 24);

        // ---- SM0: maxless shifted softmax, lane-local ----
        {
            float p[16];
            #pragma unroll
            for (int r = 0; r < 16; ++r) {
                p[r] = __builtin_amdgcn_exp2f(sc[r] * K2 - SH2);
                lp4[r & 3] += p[r];
            }
            p[0] *= a00[0]; p[1] *= a00[1]; p[2]  *= a00[2]; p[3]  *= a00[3];
            p[4] *= a01[0]; p[5] *= a01[1]; p[6]  *= a01[2]; p[7]  *= a01[3];
            p[8] *= a02[0]; p[9] *= a02[1]; p[10] *= a02[2]; p[11] *= a02[3];
            p[12]*= a03[0]; p[13]*= a03[1]; p[14] *= a03[2]; p[15] *= a03[3];
            u32 A0 = pkrtz(p[0],  p[1]),  A1 = pkrtz(p[2],  p[3]);
            u32 B0 = pkrtz(p[4],  p[5]),  B1 = pkrtz(p[6],  p[7]);
            u32 A2 = pkrtz(p[8],  p[9]),  A3 = pkrtz(p[10], p[11]);
            u32 B2 = pkrtz(p[12], p[13]), B3 = pkrtz(p[14], p[15]);
            u32 sA0 = (u32)__shfl_xor((int)A0, 32), sA1 = (u32)__shfl_xor((int)A1, 32);
            u32 sB0 = (u32)__shfl_xor((int)B0, 32), sB1 = (u32)__shfl_xor((int)B1, 32);
            u32 sA2 = (u32)__shfl_xor((int)A2, 32), sA3 = (u32)__shfl_xor((int)A3, 32);
            u32 sB2 = (u32)__shfl_xor((int)B2, 32), sB3 = (u32)__shfl_xor((int)B3, 32);
            u32x4 e, o;
            e[0] = hi2 ? sB0 : A0;  e[1] = hi2 ? sB1 : A1;
            e[2] = hi2 ? B0 : sA0;  e[3] = hi2 ? B1 : sA1;
            o[0] = hi2 ? sB2 : A2;  o[1] = hi2 ? sB3 : A3;
            o[2] = hi2 ? B2 : sA2;  o[3] = hi2 ? B3 : sA3;
            pa[0] = __builtin_bit_cast(short8v, e);
            pa[1] = __builtin_bit_cast(short8v, o);
        }

        // ---- PV ks=0,1 (needs only pa[0],pa[1]) — feeds MFMA pipe during mb1 ----
        #pragma unroll
        for (int ks = 0; ks < 2; ++ks) {
            short4v v0 = *(const short4v*)(sKTH + (l31 * 68 + ks*16 + hi2*8) * 2);
            short4v v1 = *(const short4v*)(sKTH + (l31 * 68 + ks*16 + hi2*8 + 4) * 2);
            agg0 = mfmah(pa[ks], cat44(v0, v1), agg0);
            short4v w0 = *(const short4v*)(sKTH + ((32 + l31) * 68 + ks*16 + hi2*8) * 2);
            short4v w1 = *(const short4v*)(sKTH + ((32 + l31) * 68 + ks*16 + hi2*8 + 4) * 2);
            agg1 = mfmah(pa[ks], cat44(w0, w1), agg1);
        }

        // ---- QK1: S^T rows m=32..63 ----
        #pragma unroll
        for (int i = 0; i < 16; ++i) sc[i] = 0.f;
        #pragma unroll
        for (int ks = 0; ks < 4; ++ks) {
            short4v k0 = *(const short4v*)(sKH + ((32 + l31) * 68 + ks*16 + hi2*8) * 2);
            short4v k1 = *(const short4v*)(sKH + ((32 + l31) * 68 + ks*16 + hi2*8 + 4) * 2);
            short4v q0 = *(const short4v*)(sKL + ((32 + l31) * 68 + ks*16 + hi2*8) * 2);
            short4v q1 = *(const short4v*)(sKL + ((32 + l31) * 68 + ks*16 + hi2*8 + 4) * 2);
            sc = mfmah(cat44(k0, k1), xnH[ks], sc);
            sc = mfmah(cat44(q0, q1), xnH[ks], sc);
        }

        // ---- SM1 ----
        {
            float p[16];
            #pragma unroll
            for (int r = 0; r < 16; ++r) {
                p[r] = __builtin_amdgcn_exp2f(sc[r] * K2 - SH2);
                lp4[r & 3] += p[r];
            }
            p[0] *= a10[0]; p[1] *= a10[1]; p[2]  *= a10[2]; p[3]  *= a10[3];
            p[4] *= a11[0]; p[5] *= a11[1]; p[6]  *= a11[2]; p[7]  *= a11[3];
            p[8] *= a12[0]; p[9] *= a12[1]; p[10] *= a12[2]; p[11] *= a12[3];
            p[12]*= a13[0]; p[13]*= a13[1]; p[14] *= a13[2]; p[15] *= a13[3];
            u32 A0 = pkrtz(p[0],  p[1]),  A1 = pkrtz(p[2],  p[3]);
            u32 B0 = pkrtz(p[4],  p[5]),  B1 = pkrtz(p[6],  p[7]);
            u32 A2 = pkrtz(p[8],  p[9]),  A3 = pkrtz(p[10], p[11]);
            u32 B2 = pkrtz(p[12], p[13]), B3 = pkrtz(p[14], p[15]);
            u32 sA0 = (u32)__shfl_xor((int)A0, 32), sA1 = (u32)__shfl_xor((int)A1, 32);
            u32 sB0 = (u32)__shfl_xor((int)B0, 32), sB1 = (u32)__shfl_xor((int)B1, 32);
            u32 sA2 = (u32)__shfl_xor((int)A2, 32), sA3 = (u32)__shfl_xor((int)A3, 32);
            u32 sB2 = (u32)__shfl_xor((int)B2, 32), sB3 = (u32)__shfl_xor((int)B3, 32);
            u32x4 e, o;
            e[0] = hi2 ? sB0 : A0;  e[1] = hi2 ? sB1 : A1;
            e[2] = hi2 ? B0 : sA0;  e[3] = hi2 ? B1 : sA1;
            o[0] = hi2 ? sB2 : A2;  o[1] = hi2 ? sB3 : A3;
            o[2] = hi2 ? B2 : sA2;  o[3] = hi2 ? B3 : sA3;
            pa[2] = __builtin_bit_cast(short8v, e);
            pa[3] = __builtin_bit_cast(short8v, o);
        }

        // ---- PV ks=2,3 ----
        #pragma unroll
        for (int ks = 2; ks < 4; ++ks) {
            short4v v0 = *(const short4v*)(sKTH + (l31 * 68 + ks*16 + hi2*8) * 2);
            short4v v1 = *(const short4v*)(sKTH + (l31 * 68 + ks*16 + hi2*8 + 4) * 2);
            agg0 = mfmah(pa[ks], cat44(v0, v1), agg0);
            short4v w0 = *(const short4v*)(sKTH + ((32 + l31) * 68 + ks*16 + hi2*8) * 2);
            short4v w1 = *(const short4v*)(sKTH + ((32 + l31) * 68 + ks*16 + hi2*8 + 4) * 2);
            agg1 = mfmah(pa[ks], cat44(w0, w1), agg1);
        }

        // ---- convert next tile NOW (register-only; before the stall window) ----
        if (mt < 7) STAGE_CONVERT(p0, p1, p2, p3)

        __syncthreads();                       // all waves done reading tile mt
        if (mt < 7) STAGE_LDS_WRITE
        __syncthreads();                       // tile mt+1 visible
    }

    // ---- epilogue ----
    float lpart = (lp4[0] + lp4[1]) + (lp4[2] + lp4[3]);
    float lf = lpart + __shfl_xor(lpart, 32);
    if (hi2 == 0) linvLDS[32 * w + l31] = 0.125f / lf;   // fold post-softmax 1/8
    __syncthreads();                                      // main-loop LDS free; linv visible

    // normalized agg -> sA (fp16 hi only)
    #pragma unroll
    for (int r = 0; r < 16; ++r) {
        int row = 32 * w + (r & 3) + 8 * (r >> 2) + 4 * hi2;
        float nv = linvLDS[row];
        _Float16 h0 = (_Float16)(agg0[r] * nv);
        _Float16 h1 = (_Float16)(agg1[r] * nv);
        *(short*)(sA + (row * 68 + l31) * 2)      = __builtin_bit_cast(short, h0);
        *(short*)(sA + (row * 68 + 32 + l31) * 2) = __builtin_bit_cast(short, h1);
    }
    __syncthreads();

    // A-frags: lane = n reads its own row's f-slices
    short8v gH[4];
    #pragma unroll
    for (int ks = 0; ks < 4; ++ks) {
        short4v a0 = *(const short4v*)(sA + ((32*w + l31) * 68 + ks*16 + hi2*8) * 2);
        short4v a1 = *(const short4v*)(sA + ((32*w + l31) * 68 + ks*16 + hi2*8 + 4) * 2);
        gH[ks] = cat44(a0, a1);
    }

    // out = relu(aggN * W^T): B = W row per lane, 2-term W-split (Wh + Wl)
    #pragma unroll
    for (int ob = 0; ob < 2; ++ob) {
        short8v wHreg[4], wLreg[4];
        #pragma unroll
        for (int ks = 0; ks < 4; ++ks) {
            const float* wp = W + (size_t)(ob * 32 + l31) * FF + ks * 16 + hi2 * 8;
            f32x4 wa = *(const f32x4*)(wp);
            f32x4 wb = *(const f32x4*)(wp + 4);
            short4v h0, l0, h1, l1;
            cvt4h(wa, h0, l0);
            cvt4h(wb, h1, l1);
            wHreg[ks] = cat44(h0, h1);
            wLreg[ks] = cat44(l0, l1);
        }
        f32x16 oc;
        #pragma unroll
        for (int i = 0; i < 16; ++i) oc[i] = 0.f;
        #pragma unroll
        for (int ks = 0; ks < 4; ++ks) {
            oc = mfmah(gH[ks], wHreg[ks], oc);
            oc = mfmah(gH[ks], wLreg[ks], oc);
        }
        #pragma unroll
        for (int r = 0; r < 16; ++r) {
            int row = 32 * w + (r & 3) + 8 * (r >> 2) + 4 * hi2;
            out[((size_t)(b * NN + n0 + row) * TT + t) * FF + 32 * ob + l31] = fmaxf(oc[r], 0.f);
        }
    }
#undef STAGE_CONVERT
#undef STAGE_LDS_WRITE
}

extern "C" void kernel_launch(void* const* d_in, const int* in_sizes, int n_in,
                              void* d_out, int out_size, void* d_ws, size_t ws_size,
                              hipStream_t stream) {
    const float* x   = (const float*)d_in[0];
    const float* adj = (const float*)d_in[1];
    const float* W   = (const float*)d_in[2];
    float* outp = (float*)d_out;

    sgcn11<<<dim3(1536), dim3(256), 0, stream>>>(x, adj, W, outp);
}

// Round 12
// 90.898 us; speedup vs baseline: 2.6902x; 1.0840x over previous
//
#include <hip/hip_runtime.h>
#include <math.h>

// B,N,T,F = 32,512,12,64
#define NN 512
#define TT 12
#define FF 64

typedef float  f32x4   __attribute__((ext_vector_type(4)));
typedef float  f32x16  __attribute__((ext_vector_type(16)));
typedef short  short4v __attribute__((ext_vector_type(4)));
typedef short  short8v __attribute__((ext_vector_type(8)));
typedef _Float16 h16x4 __attribute__((ext_vector_type(4)));
typedef _Float16 h16x8 __attribute__((ext_vector_type(8)));
typedef unsigned int u32;
typedef u32    u32x4   __attribute__((ext_vector_type(4)));

static __device__ __forceinline__ u32 pkrtz(float a, float b) {
    u32 p;
    asm("v_cvt_pkrtz_f16_f32 %0, %1, %2" : "=v"(p) : "v"(a), "v"(b));
    return p;   // low16 = fp16(a), high16 = fp16(b)
}
// f32x4 -> fp16 hi (RNE) + fp16 residual (exact subtract, then RNE)
static __device__ __forceinline__ void cvt4h(f32x4 v, short4v& h, short4v& lo) {
    h16x4 hh, ll;
    #pragma unroll
    for (int j = 0; j < 4; ++j) {
        _Float16 a = (_Float16)v[j];
        hh[j] = a;
        ll[j] = (_Float16)(v[j] - (float)a);
    }
    h  = __builtin_bit_cast(short4v, hh);
    lo = __builtin_bit_cast(short4v, ll);
}
static __device__ __forceinline__ short8v cat44(short4v a, short4v b) {
    return __builtin_shufflevector(a, b, 0, 1, 2, 3, 4, 5, 6, 7);
}
static __device__ __forceinline__ f32x16 mfmah(short8v a, short8v b, f32x16 c) {
    return __builtin_amdgcn_mfma_f32_32x32x16_f16(
        __builtin_bit_cast(h16x8, a), __builtin_bit_cast(h16x8, b), c, 0, 0, 0);
}

// LDS: two K-tile buffers (each: sKH [64][68] @+0, sKL @+8704, sKTH @+17408 = 26112 B)
//      buf0 @0, buf1 @26112, linv f32[128] @52224.  Total 52736 -> 3 blocks/CU.
// Epilogue: sA [128][68] fp16 @0 (reuses buf0 region).
#define BUFSZ 26112
#define SMEM_BYTES 52736

__global__ __launch_bounds__(256, 3)
void sgcn12(const float* __restrict__ x, const float* __restrict__ adj,
            const float* __restrict__ W, float* __restrict__ out)
{
    __shared__ __align__(16) char smem[SMEM_BYTES];
    char* sA = smem;
    float* linvLDS = (float*)(smem + 2 * BUFSZ);

    // XCD-grouped swizzle: 4 WGs per (b,t) adjacent on one XCD
    const int d   = blockIdx.x;
    const int xcd = d & 7;
    const int s   = d >> 3;
    const int G   = xcd + 8 * (s >> 2);   // 0..383 = b*12 + t
    const int mem = s & 3;
    const int t = G % TT, b = G / TT;
    const int n0 = mem * 128;

    const int tid = threadIdx.x;
    const int w   = tid >> 6;             // wave -> n-rows 32w..32w+31
    const int l31 = tid & 31;
    const int hi2 = (tid >> 5) & 1;
    const int fq  = tid & 15;             // staging: f-quad (floats 4fq..4fq+3)
    const int mq  = tid >> 4;             // staging: rows 4mq..4mq+3
    const int myn = n0 + 32 * w + l31;    // this lane's n (S^T col / PV A row)

    const float K2 = 0.18033688011112042f;   // 0.125 * log2(e)
    // uniform logit shift (softmax-invariant): keeps max P ~ e^10 < fp16 max 65504
    const float SH2 = 8.656170245333781f;    // 6 * log2(e)

    // ---- prologue: xn fragments (fp16 hi) ----
    const float* xnrow = x + ((size_t)(b * NN + myn) * TT + t) * FF;
    short8v xnH[4];
    #pragma unroll
    for (int ks = 0; ks < 4; ++ks) {
        f32x4 a0 = *(const f32x4*)(xnrow + ks * 16 + hi2 * 8);
        f32x4 a1 = *(const f32x4*)(xnrow + ks * 16 + hi2 * 8 + 4);
        short4v h0, l0, h1, l1;
        cvt4h(a0, h0, l0);
        cvt4h(a1, h1, l1);
        xnH[ks] = cat44(h0, h1);
    }

    // staged-tile register state (converted early, written to the idle buffer)
    short4v sh[4], sq[4];

#define STAGE_CONVERT(L0, L1, L2, L3)                                          \
    { cvt4h(L0, sh[0], sq[0]); cvt4h(L1, sh[1], sq[1]);                        \
      cvt4h(L2, sh[2], sq[2]); cvt4h(L3, sh[3], sq[3]); }

#define STAGE_LDS_WRITE(DST)                                                   \
  {                                                                            \
    char* dKH = (DST);                                                         \
    char* dKL = (DST) + 8704;                                                  \
    char* dKT = (DST) + 17408;                                                 \
    _Pragma("unroll")                                                          \
    for (int j = 0; j < 4; ++j) {                                              \
        *(short4v*)(dKH + ((4*mq+j)*68 + 4*fq) * 2) = sh[j];                   \
        *(short4v*)(dKL + ((4*mq+j)*68 + 4*fq) * 2) = sq[j];                   \
    }                                                                          \
    _Pragma("unroll")                                                          \
    for (int j = 0; j < 4; ++j) {                                              \
        short4v th; th[0]=sh[0][j]; th[1]=sh[1][j]; th[2]=sh[2][j]; th[3]=sh[3][j]; \
        *(short4v*)(dKT + ((4*fq+j)*68 + 4*mq) * 2) = th;                      \
    }                                                                          \
  }

    {
        const float* xst = x + ((size_t)(b * NN + 4 * mq) * TT + t) * FF + 4 * fq;
        f32x4 ld0 = *(const f32x4*)(xst);
        f32x4 ld1 = *(const f32x4*)(xst + TT * FF);
        f32x4 ld2 = *(const f32x4*)(xst + 2 * TT * FF);
        f32x4 ld3 = *(const f32x4*)(xst + 3 * TT * FF);
        STAGE_CONVERT(ld0, ld1, ld2, ld3)
        STAGE_LDS_WRITE(smem)
    }
    __syncthreads();

    float lp4[4] = {0.f, 0.f, 0.f, 0.f};     // 4-way partial denominator
    f32x16 agg0a, agg0b, agg1a, agg1b;       // split accumulator chains
    #pragma unroll
    for (int i = 0; i < 16; ++i) { agg0a[i]=0.f; agg0b[i]=0.f; agg1a[i]=0.f; agg1b[i]=0.f; }

    unsigned bo = 0;
    for (int mt = 0; mt < 8; ++mt) {
        const int m0 = mt * 64;
        const char* bKH = smem + bo;
        const char* bKL = smem + bo + 8704;
        const char* bKT = smem + bo + 17408;

        // T14: issue next-tile staging loads first (longest latency)
        f32x4 p0, p1, p2, p3;
        if (mt < 7) {
            const float* xs = x + ((size_t)(b * NN + m0 + 64 + 4 * mq) * TT + t) * FF + 4 * fq;
            p0 = *(const f32x4*)(xs);
            p1 = *(const f32x4*)(xs + TT * FF);
            p2 = *(const f32x4*)(xs + 2 * TT * FF);
            p3 = *(const f32x4*)(xs + 3 * TT * FF);
        }

        // adj prefetch for mb0 BEFORE the MFMAs (hidden under QK0)
        const float* arow0 = adj + (size_t)myn * NN + m0 + 4 * hi2;
        f32x4 a00 = *(const f32x4*)(arow0);
        f32x4 a01 = *(const f32x4*)(arow0 + 8);
        f32x4 a02 = *(const f32x4*)(arow0 + 16);
        f32x4 a03 = *(const f32x4*)(arow0 + 24);

        short8v pa[4];

        // ---- QK0: S^T rows m=0..31; two independent MFMA chains ----
        f32x16 scA, scB;
        #pragma unroll
        for (int i = 0; i < 16; ++i) { scA[i] = 0.f; scB[i] = 0.f; }
        #pragma unroll
        for (int ks = 0; ks < 2; ++ks) {
            short4v k0 = *(const short4v*)(bKH + (l31 * 68 + ks*16 + hi2*8) * 2);
            short4v k1 = *(const short4v*)(bKH + (l31 * 68 + ks*16 + hi2*8 + 4) * 2);
            short4v q0 = *(const short4v*)(bKL + (l31 * 68 + ks*16 + hi2*8) * 2);
            short4v q1 = *(const short4v*)(bKL + (l31 * 68 + ks*16 + hi2*8 + 4) * 2);
            scA = mfmah(cat44(k0, k1), xnH[ks], scA);
            scA = mfmah(cat44(q0, q1), xnH[ks], scA);
        }
        #pragma unroll
        for (int ks = 2; ks < 4; ++ks) {
            short4v k0 = *(const short4v*)(bKH + (l31 * 68 + ks*16 + hi2*8) * 2);
            short4v k1 = *(const short4v*)(bKH + (l31 * 68 + ks*16 + hi2*8 + 4) * 2);
            short4v q0 = *(const short4v*)(bKL + (l31 * 68 + ks*16 + hi2*8) * 2);
            short4v q1 = *(const short4v*)(bKL + (l31 * 68 + ks*16 + hi2*8 + 4) * 2);
            scB = mfmah(cat44(k0, k1), xnH[ks], scB);
            scB = mfmah(cat44(q0, q1), xnH[ks], scB);
        }

        // adj prefetch for mb1 (issued now, consumed after SM0+PV01)
        const float* arow1 = adj + (size_t)myn * NN + m0 + 32 + 4 * hi2;
        f32x4 a10 = *(const f32x4*)(arow1);
        f32x4 a11 = *(const f32x4*)(arow1 + 8);
        f32x4 a12 = *(const f32x4*)(arow1 + 16);
        f32x4 a13 = *(const f32x4*)(arow1 + 24);

        // ---- SM0: maxless shifted softmax, lane-local ----
        {
            f32x16 sc = scA + scB;
            float p[16];
            #pragma unroll
            for (int r = 0; r < 16; ++r) {
                p[r] = __builtin_amdgcn_exp2f(sc[r] * K2 - SH2);
                lp4[r & 3] += p[r];
            }
            p[0] *= a00[0]; p[1] *= a00[1]; p[2]  *= a00[2]; p[3]  *= a00[3];
            p[4] *= a01[0]; p[5] *= a01[1]; p[6]  *= a01[2]; p[7]  *= a01[3];
            p[8] *= a02[0]; p[9] *= a02[1]; p[10] *= a02[2]; p[11] *= a02[3];
            p[12]*= a03[0]; p[13]*= a03[1]; p[14] *= a03[2]; p[15] *= a03[3];
            u32 A0 = pkrtz(p[0],  p[1]),  A1 = pkrtz(p[2],  p[3]);
            u32 B0 = pkrtz(p[4],  p[5]),  B1 = pkrtz(p[6],  p[7]);
            u32 A2 = pkrtz(p[8],  p[9]),  A3 = pkrtz(p[10], p[11]);
            u32 B2 = pkrtz(p[12], p[13]), B3 = pkrtz(p[14], p[15]);
            u32 sA0 = (u32)__shfl_xor((int)A0, 32), sA1 = (u32)__shfl_xor((int)A1, 32);
            u32 sB0 = (u32)__shfl_xor((int)B0, 32), sB1 = (u32)__shfl_xor((int)B1, 32);
            u32 sA2 = (u32)__shfl_xor((int)A2, 32), sA3 = (u32)__shfl_xor((int)A3, 32);
            u32 sB2 = (u32)__shfl_xor((int)B2, 32), sB3 = (u32)__shfl_xor((int)B3, 32);
            u32x4 e, o;
            e[0] = hi2 ? sB0 : A0;  e[1] = hi2 ? sB1 : A1;
            e[2] = hi2 ? B0 : sA0;  e[3] = hi2 ? B1 : sA1;
            o[0] = hi2 ? sB2 : A2;  o[1] = hi2 ? sB3 : A3;
            o[2] = hi2 ? B2 : sA2;  o[3] = hi2 ? B3 : sA3;
            pa[0] = __builtin_bit_cast(short8v, e);
            pa[1] = __builtin_bit_cast(short8v, o);
        }

        // ---- PV ks=0,1 (alternating acc chains) ----
        {
            short4v v0 = *(const short4v*)(bKT + (l31 * 68 + hi2*8) * 2);
            short4v v1 = *(const short4v*)(bKT + (l31 * 68 + hi2*8 + 4) * 2);
            agg0a = mfmah(pa[0], cat44(v0, v1), agg0a);
            short4v w0 = *(const short4v*)(bKT + ((32 + l31) * 68 + hi2*8) * 2);
            short4v w1 = *(const short4v*)(bKT + ((32 + l31) * 68 + hi2*8 + 4) * 2);
            agg1a = mfmah(pa[0], cat44(w0, w1), agg1a);
            short4v v2 = *(const short4v*)(bKT + (l31 * 68 + 16 + hi2*8) * 2);
            short4v v3 = *(const short4v*)(bKT + (l31 * 68 + 16 + hi2*8 + 4) * 2);
            agg0b = mfmah(pa[1], cat44(v2, v3), agg0b);
            short4v w2 = *(const short4v*)(bKT + ((32 + l31) * 68 + 16 + hi2*8) * 2);
            short4v w3 = *(const short4v*)(bKT + ((32 + l31) * 68 + 16 + hi2*8 + 4) * 2);
            agg1b = mfmah(pa[1], cat44(w2, w3), agg1b);
        }

        // ---- QK1: S^T rows m=32..63 ----
        #pragma unroll
        for (int i = 0; i < 16; ++i) { scA[i] = 0.f; scB[i] = 0.f; }
        #pragma unroll
        for (int ks = 0; ks < 2; ++ks) {
            short4v k0 = *(const short4v*)(bKH + ((32 + l31) * 68 + ks*16 + hi2*8) * 2);
            short4v k1 = *(const short4v*)(bKH + ((32 + l31) * 68 + ks*16 + hi2*8 + 4) * 2);
            short4v q0 = *(const short4v*)(bKL + ((32 + l31) * 68 + ks*16 + hi2*8) * 2);
            short4v q1 = *(const short4v*)(bKL + ((32 + l31) * 68 + ks*16 + hi2*8 + 4) * 2);
            scA = mfmah(cat44(k0, k1), xnH[ks], scA);
            scA = mfmah(cat44(q0, q1), xnH[ks], scA);
        }
        #pragma unroll
        for (int ks = 2; ks < 4; ++ks) {
            short4v k0 = *(const short4v*)(bKH + ((32 + l31) * 68 + ks*16 + hi2*8) * 2);
            short4v k1 = *(const short4v*)(bKH + ((32 + l31) * 68 + ks*16 + hi2*8 + 4) * 2);
            short4v q0 = *(const short4v*)(bKL + ((32 + l31) * 68 + ks*16 + hi2*8) * 2);
            short4v q1 = *(const short4v*)(bKL + ((32 + l31) * 68 + ks*16 + hi2*8 + 4) * 2);
            scB = mfmah(cat44(k0, k1), xnH[ks], scB);
            scB = mfmah(cat44(q0, q1), xnH[ks], scB);
        }

        // ---- SM1 ----
        {
            f32x16 sc = scA + scB;
            float p[16];
            #pragma unroll
            for (int r = 0; r < 16; ++r) {
                p[r] = __builtin_amdgcn_exp2f(sc[r] * K2 - SH2);
                lp4[r & 3] += p[r];
            }
            p[0] *= a10[0]; p[1] *= a10[1]; p[2]  *= a10[2]; p[3]  *= a10[3];
            p[4] *= a11[0]; p[5] *= a11[1]; p[6]  *= a11[2]; p[7]  *= a11[3];
            p[8] *= a12[0]; p[9] *= a12[1]; p[10] *= a12[2]; p[11] *= a12[3];
            p[12]*= a13[0]; p[13]*= a13[1]; p[14] *= a13[2]; p[15] *= a13[3];
            u32 A0 = pkrtz(p[0],  p[1]),  A1 = pkrtz(p[2],  p[3]);
            u32 B0 = pkrtz(p[4],  p[5]),  B1 = pkrtz(p[6],  p[7]);
            u32 A2 = pkrtz(p[8],  p[9]),  A3 = pkrtz(p[10], p[11]);
            u32 B2 = pkrtz(p[12], p[13]), B3 = pkrtz(p[14], p[15]);
            u32 sA0 = (u32)__shfl_xor((int)A0, 32), sA1 = (u32)__shfl_xor((int)A1, 32);
            u32 sB0 = (u32)__shfl_xor((int)B0, 32), sB1 = (u32)__shfl_xor((int)B1, 32);
            u32 sA2 = (u32)__shfl_xor((int)A2, 32), sA3 = (u32)__shfl_xor((int)A3, 32);
            u32 sB2 = (u32)__shfl_xor((int)B2, 32), sB3 = (u32)__shfl_xor((int)B3, 32);
            u32x4 e, o;
            e[0] = hi2 ? sB0 : A0;  e[1] = hi2 ? sB1 : A1;
            e[2] = hi2 ? B0 : sA0;  e[3] = hi2 ? B1 : sA1;
            o[0] = hi2 ? sB2 : A2;  o[1] = hi2 ? sB3 : A3;
            o[2] = hi2 ? B2 : sA2;  o[3] = hi2 ? B3 : sA3;
            pa[2] = __builtin_bit_cast(short8v, e);
            pa[3] = __builtin_bit_cast(short8v, o);
        }

        // ---- PV ks=2,3 ----
        {
            short4v v0 = *(const short4v*)(bKT + (l31 * 68 + 32 + hi2*8) * 2);
            short4v v1 = *(const short4v*)(bKT + (l31 * 68 + 32 + hi2*8 + 4) * 2);
            agg0a = mfmah(pa[2], cat44(v0, v1), agg0a);
            short4v w0 = *(const short4v*)(bKT + ((32 + l31) * 68 + 32 + hi2*8) * 2);
            short4v w1 = *(const short4v*)(bKT + ((32 + l31) * 68 + 32 + hi2*8 + 4) * 2);
            agg1a = mfmah(pa[2], cat44(w0, w1), agg1a);
            short4v v2 = *(const short4v*)(bKT + (l31 * 68 + 48 + hi2*8) * 2);
            short4v v3 = *(const short4v*)(bKT + (l31 * 68 + 48 + hi2*8 + 4) * 2);
            agg0b = mfmah(pa[3], cat44(v2, v3), agg0b);
            short4v w2 = *(const short4v*)(bKT + ((32 + l31) * 68 + 48 + hi2*8) * 2);
            short4v w3 = *(const short4v*)(bKT + ((32 + l31) * 68 + 48 + hi2*8 + 4) * 2);
            agg1b = mfmah(pa[3], cat44(w2, w3), agg1b);
        }

        // ---- stage next tile into the idle buffer (no barrier needed first) ----
        if (mt < 7) {
            STAGE_CONVERT(p0, p1, p2, p3)
            STAGE_LDS_WRITE(smem + (bo ^ BUFSZ))
        }
        __syncthreads();              // end of tile: reads of buf done + writes visible
        bo ^= BUFSZ;
    }

    // ---- epilogue ----
    f32x16 agg0 = agg0a + agg0b;
    f32x16 agg1 = agg1a + agg1b;
    float lpart = (lp4[0] + lp4[1]) + (lp4[2] + lp4[3]);
    float lf = lpart + __shfl_xor(lpart, 32);
    if (hi2 == 0) linvLDS[32 * w + l31] = 0.125f / lf;   // fold post-softmax 1/8
    __syncthreads();                                      // linv visible; main-loop LDS free

    // normalized agg -> sA (fp16 hi only)
    #pragma unroll
    for (int r = 0; r < 16; ++r) {
        int row = 32 * w + (r & 3) + 8 * (r >> 2) + 4 * hi2;
        float nv = linvLDS[row];
        _Float16 h0 = (_Float16)(agg0[r] * nv);
        _Float16 h1 = (_Float16)(agg1[r] * nv);
        *(short*)(sA + (row * 68 + l31) * 2)      = __builtin_bit_cast(short, h0);
        *(short*)(sA + (row * 68 + 32 + l31) * 2) = __builtin_bit_cast(short, h1);
    }
    __syncthreads();

    // A-frags: lane = n reads its own row's f-slices
    short8v gH[4];
    #pragma unroll
    for (int ks = 0; ks < 4; ++ks) {
        short4v a0 = *(const short4v*)(sA + ((32*w + l31) * 68 + ks*16 + hi2*8) * 2);
        short4v a1 = *(const short4v*)(sA + ((32*w + l31) * 68 + ks*16 + hi2*8 + 4) * 2);
        gH[ks] = cat44(a0, a1);
    }

    // out = relu(aggN * W^T): B = W row per lane, 2-term W-split (Wh + Wl)
    #pragma unroll
    for (int ob = 0; ob < 2; ++ob) {
        short8v wHreg[4], wLreg[4];
        #pragma unroll
        for (int ks = 0; ks < 4; ++ks) {
            const float* wp = W + (size_t)(ob * 32 + l31) * FF + ks * 16 + hi2 * 8;
            f32x4 wa = *(const f32x4*)(wp);
            f32x4 wb = *(const f32x4*)(wp + 4);
            short4v h0, l0, h1, l1;
            cvt4h(wa, h0, l0);
            cvt4h(wb, h1, l1);
            wHreg[ks] = cat44(h0, h1);
            wLreg[ks] = cat44(l0, l1);
        }
        f32x16 oc;
        #pragma unroll
        for (int i = 0; i < 16; ++i) oc[i] = 0.f;
        #pragma unroll
        for (int ks = 0; ks < 4; ++ks) {
            oc = mfmah(gH[ks], wHreg[ks], oc);
            oc = mfmah(gH[ks], wLreg[ks], oc);
        }
        #pragma unroll
        for (int r = 0; r < 16; ++r) {
            int row = 32 * w + (r & 3) + 8 * (r >> 2) + 4 * hi2;
            out[((size_t)(b * NN + n0 + row) * TT + t) * FF + 32 * ob + l31] = fmaxf(oc[r], 0.f);
        }
    }
#undef STAGE_CONVERT
#undef STAGE_LDS_WRITE
}

extern "C" void kernel_launch(void* const* d_in, const int* in_sizes, int n_in,
                              void* d_out, int out_size, void* d_ws, size_t ws_size,
                              hipStream_t stream) {
    const float* x   = (const float*)d_in[0];
    const float* adj = (const float*)d_in[1];
    const float* W   = (const float*)d_in[2];
    float* outp = (float*)d_out;

    sgcn12<<<dim3(1536), dim3(256), 0, stream>>>(x, adj, W, outp);
}